// Round 3
// baseline (249.529 us; speedup 1.0000x reference)
//
#include <hip/hip_runtime.h>
#include <math.h>

// Problem constants (from reference): N=100000, S=64, Q=50, P=3
#define N_Q 50
#define N_P 3
#define N_S 64
#define ROW 150        // Q*P floats per pauli word
#define BLK_ROWS 64    // rows per block = 4 waves x 16 rows
#define THREADS 256
#define WAVES 4
#define RPW 16         // rows per wave (2 streams of 8)

// ws layout (bytes):
//   [0      .. 12504)   partials double[1563]
//   [12544  .. +4)      done-counter int (zeroed by precompute each launch)
//   [12608  .. +38400)  HP   float[Q][S][3]  normalized heads, q-major
//   [51008  .. +256)    hrv  float[S]        smoothed head ratios
#define WS_CNT_OFF 12544
#define WS_HP_OFF 12608
#define WS_HRV_OFF 51008

__device__ __forceinline__ float softplus20(float x) {
    float z = x * 20.0f;
    return fmaxf(z, 0.0f) + log1pf(expf(-fabsf(z)));  // stable softplus
}

__global__ void precompute_kernel(const float* __restrict__ heads_param,
                                  const float* __restrict__ hr_param,
                                  float* __restrict__ HP,
                                  float* __restrict__ hrv,
                                  int* __restrict__ cnt) {
    const int tid = threadIdx.x;
    if (blockIdx.x == 0) {
        if (tid == 0) *cnt = 0;  // ws is re-poisoned every launch
        if (tid < N_S) {
            float sp = softplus20(hr_param[tid]);
            float tot = sp;
            #pragma unroll
            for (int off = 32; off; off >>= 1) tot += __shfl_xor(tot, off);
            float hr = sp / fmaxf(tot, 1e-12f);
            hrv[tid] = (hr + 0.001f / (float)N_S) / 1.001f;
        }
    }
    // EXACT reference semantics: h_p = sp_p / max(sum, EPS).
    int idx = blockIdx.x * blockDim.x + tid;
    if (idx < N_S * N_Q) {
        int q = idx / N_S;
        int s = idx - q * N_S;
        const float* hp = heads_param + ((size_t)s * N_Q + q) * N_P;
        float sp0 = softplus20(hp[0]);
        float sp1 = softplus20(hp[1]);
        float sp2 = softplus20(hp[2]);
        float denom = fmaxf(sp0 + sp1 + sp2, 1e-12f);
        float* o = HP + ((size_t)q * N_S + s) * 3;
        o[0] = sp0 / denom;
        o[1] = sp1 / denom;
        o[2] = sp2 / denom;
    }
}

// Load chunk CH (5 q = 15 floats) of a row from a WAVE-UNIFORM pointer.
// Uniform readonly address -> compiler emits s_load_dwordxN into SGPRs.
template<int CH>
__device__ __forceinline__ void loadc(const float* __restrict__ p, float (&b)[15]) {
    #pragma unroll
    for (int k = 0; k < 15; ++k) b[k] = p[CH * 15 + k];
}

// Apply chunk C (q = 5C .. 5C+4) to one prod chain. h is per-lane (lane = s),
// b is wave-uniform (SGPR). Math order EXACTLY matches the verified kernel:
//   t = fmaf(H0, A0, fmaf(H1, A1, H2*A2)); prod *= t;  q ascending.
template<int C>
__device__ __forceinline__ void chunk5(const float (&h)[N_Q][N_P],
                                       const float (&b)[15], float& prod) {
    #pragma unroll
    for (int j = 0; j < 5; ++j) {
        float t = h[5 * C + j][2] * b[3 * j + 2];
        t = fmaf(h[5 * C + j][1], b[3 * j + 1], t);
        t = fmaf(h[5 * C + j][0], b[3 * j + 0], t);
        prod *= t;
    }
}

__global__ __launch_bounds__(THREADS, 2) void main_kernel(
    const float* __restrict__ A, const float* __restrict__ coeff,
    const float* __restrict__ HP, const float* __restrict__ hrv,
    double* __restrict__ partials, int* __restrict__ cnt,
    float* __restrict__ out, int N) {
    // prod transpose buffer: [wave][row][s], s-dim padded to 65 ->
    // write banks (row+lane)%32 (2-way, free), read banks (lane+i)%32 (free).
    __shared__ float plds[WAVES][RPW][N_S + 1];   // 16640 B
    __shared__ double redf[WAVES];
    __shared__ int isLast;

    const int tid = threadIdx.x;
    const int lane = tid & 63;
    const int wq = __builtin_amdgcn_readfirstlane(tid >> 6);
    const int wbase = blockIdx.x * BLK_ROWS + RPW * wq;  // first row of this wave

    // --- per-lane H: lane = s, all 50 q in registers (150 VGPR), loaded once ---
    float h[N_Q][N_P];
    {
        const float* __restrict__ HPl = HP + 3 * lane;   // HP[q][s][p]
        #pragma unroll
        for (int q = 0; q < N_Q; ++q) {
            h[q][0] = HPl[q * (N_S * 3) + 0];
            h[q][1] = HPl[q * (N_S * 3) + 1];
            h[q][2] = HPl[q * (N_S * 3) + 2];
        }
    }

    // --- 2 row-streams per wave (rows rp and rp+8), chunk ping-pong prefetch ---
    float a0[15], a1[15], b0[15], b1[15];   // uniform chunks -> SGPRs
    {
        const int nA = min(wbase + 0, N - 1);
        const int nB = min(wbase + 8, N - 1);
        const float* pa = A + (size_t)nA * ROW;
        const float* pb = A + (size_t)nB * ROW;
        loadc<0>(pa, a0); loadc<0>(pb, b0);
        loadc<1>(pa, a1); loadc<1>(pb, b1);
    }

    for (int rp = 0; rp < 8; ++rp) {
        const int nA = min(wbase + rp, N - 1);
        const int nB = min(wbase + 8 + rp, N - 1);
        const float* pa = A + (size_t)nA * ROW;
        const float* pb = A + (size_t)nB * ROW;
        // next row's pointer (clamped; equals next iteration's pa/pb exactly)
        const float* panA = A + (size_t)min(nA + 1, N - 1) * ROW;
        const float* panB = A + (size_t)min(nB + 1, N - 1) * ROW;

        float prodA = 1.0f, prodB = 1.0f;
        // entry invariant: a0/b0 = chunk0, a1/b1 = chunk1 of rows nA/nB.
        // per step: compute chunk c, then refill that buffer with chunk c+2
        // (~160 cyc lead before reuse).
        chunk5<0>(h, a0, prodA); loadc<2>(pa, a0);
        chunk5<0>(h, b0, prodB); loadc<2>(pb, b0);
        chunk5<1>(h, a1, prodA); loadc<3>(pa, a1);
        chunk5<1>(h, b1, prodB); loadc<3>(pb, b1);
        chunk5<2>(h, a0, prodA); loadc<4>(pa, a0);
        chunk5<2>(h, b0, prodB); loadc<4>(pb, b0);
        chunk5<3>(h, a1, prodA); loadc<5>(pa, a1);
        chunk5<3>(h, b1, prodB); loadc<5>(pb, b1);
        chunk5<4>(h, a0, prodA); loadc<6>(pa, a0);
        chunk5<4>(h, b0, prodB); loadc<6>(pb, b0);
        chunk5<5>(h, a1, prodA); loadc<7>(pa, a1);
        chunk5<5>(h, b1, prodB); loadc<7>(pb, b1);
        chunk5<6>(h, a0, prodA); loadc<8>(pa, a0);
        chunk5<6>(h, b0, prodB); loadc<8>(pb, b0);
        chunk5<7>(h, a1, prodA); loadc<9>(pa, a1);
        chunk5<7>(h, b1, prodB); loadc<9>(pb, b1);
        chunk5<8>(h, a0, prodA); loadc<0>(panA, a0);  // next row chunk0
        chunk5<8>(h, b0, prodB); loadc<0>(panB, b0);
        chunk5<9>(h, a1, prodA); loadc<1>(panA, a1);  // next row chunk1
        chunk5<9>(h, b1, prodB); loadc<1>(panB, b1);

        plds[wq][rp][lane] = prodA;
        plds[wq][8 + rp][lane] = prodB;
    }

    // --- finalize: lanes 0..15 each own one row; EXACT cov association:
    // four 16-long fmaf chains over s ascending, then ((a0+a1)+a2)+a3. ---
    double td = 0.0;
    if (lane < RPW) {
        float acc0 = 0.0f, acc1 = 0.0f, acc2 = 0.0f, acc3 = 0.0f;
        #pragma unroll
        for (int i = 0; i < 16; ++i) {
            acc0 = fmaf(hrv[i],      plds[wq][lane][i],      acc0);
            acc1 = fmaf(hrv[i + 16], plds[wq][lane][i + 16], acc1);
            acc2 = fmaf(hrv[i + 32], plds[wq][lane][i + 32], acc2);
            acc3 = fmaf(hrv[i + 48], plds[wq][lane][i + 48], acc3);
        }
        float cov = ((acc0 + acc1) + acc2) + acc3;
        int n = wbase + lane;
        if (n < N) { float c = coeff[n]; td = (double)((c * c) / cov); }
    }
    #pragma unroll
    for (int off = 32; off; off >>= 1) td += __shfl_down(td, off);
    if (lane == 0) redf[wq] = td;
    __syncthreads();

    if (tid == 0) {
        partials[blockIdx.x] = ((redf[0] + redf[1]) + redf[2]) + redf[3];
        __threadfence();                 // release partial
        int v = atomicAdd(cnt, 1);
        isLast = (v == (int)gridDim.x - 1);
    }
    __syncthreads();

    if (isLast) {                        // last-finishing block reduces all
        __threadfence();                 // acquire
        double s = 0.0;
        for (int i = tid; i < (int)gridDim.x; i += THREADS) s += partials[i];
        #pragma unroll
        for (int off = 32; off; off >>= 1) s += __shfl_down(s, off);
        __shared__ double redg[WAVES];
        if (lane == 0) redg[tid >> 6] = s;
        __syncthreads();
        if (tid == 0) out[0] = (float)(((redg[0] + redg[1]) + redg[2]) + redg[3]);
    }
}

extern "C" void kernel_launch(void* const* d_in, const int* in_sizes, int n_in,
                              void* d_out, int out_size, void* d_ws, size_t ws_size,
                              hipStream_t stream) {
    const float* A           = (const float*)d_in[0];  // [N, Q, P]
    const float* coeff       = (const float*)d_in[1];  // [N]
    const float* heads_param = (const float*)d_in[2];  // [S, Q, P]
    const float* hr_param    = (const float*)d_in[3];  // [S]
    const int N = in_sizes[1];
    const int nblocks = (N + BLK_ROWS - 1) / BLK_ROWS;  // 1563

    char* ws = (char*)d_ws;
    double* partials = (double*)ws;
    int*   cnt = (int*)(ws + WS_CNT_OFF);
    float* HP  = (float*)(ws + WS_HP_OFF);
    float* hrv = (float*)(ws + WS_HRV_OFF);
    float* out = (float*)d_out;

    const int pre_blocks = (N_S * N_Q + THREADS - 1) / THREADS;  // 13
    precompute_kernel<<<pre_blocks, THREADS, 0, stream>>>(heads_param, hr_param,
                                                          HP, hrv, cnt);
    main_kernel<<<nblocks, THREADS, 0, stream>>>(A, coeff, HP, hrv, partials,
                                                 cnt, out, N);
}

// Round 4
// 175.107 us; speedup vs baseline: 1.4250x; 1.4250x over previous
//
#include <hip/hip_runtime.h>
#include <math.h>

// Problem constants (from reference): N=100000, S=64, Q=50, P=3
#define N_Q 50
#define N_P 3
#define N_S 64
#define ROW 150        // Q*P floats per pauli word
#define BLK_ROWS 128   // rows per block (2 per lane)
#define THREADS 512    // 8 waves; wave w handles s in [8w, 8w+8)
#define WAVES 8
#define SCHUNK 8

// ws layout (bytes):
//   [0      .. 6256)    partials double[782]
//   [6272   .. +4)      done-counter int (zeroed by precompute each launch)
//   [6336   .. +38400)  HP   float[Q][S][3]  normalized heads, q-major
//   [44736  .. +256)    hrv  float[S]        smoothed head ratios
#define WS_CNT_OFF 6272
#define WS_HP_OFF 6336
#define WS_HRV_OFF 44736

__device__ __forceinline__ float softplus20(float x) {
    float z = x * 20.0f;
    return fmaxf(z, 0.0f) + log1pf(expf(-fabsf(z)));  // stable softplus
}

__global__ void precompute_kernel(const float* __restrict__ heads_param,
                                  const float* __restrict__ hr_param,
                                  float* __restrict__ HP,
                                  float* __restrict__ hrv,
                                  int* __restrict__ cnt) {
    const int tid = threadIdx.x;
    if (blockIdx.x == 0) {
        if (tid == 0) *cnt = 0;  // ws is re-poisoned every launch
        if (tid < N_S) {
            float sp = softplus20(hr_param[tid]);
            float tot = sp;
            #pragma unroll
            for (int off = 32; off; off >>= 1) tot += __shfl_xor(tot, off);
            float hr = sp / fmaxf(tot, 1e-12f);
            hrv[tid] = (hr + 0.001f / (float)N_S) / 1.001f;
        }
    }
    // EXACT reference semantics: h_p = sp_p / max(sum, EPS); when the clamp
    // fires the row does NOT sum to 1, so all three components are stored.
    int idx = blockIdx.x * blockDim.x + tid;
    if (idx < N_S * N_Q) {
        int q = idx / N_S;
        int s = idx - q * N_S;
        const float* hp = heads_param + ((size_t)s * N_Q + q) * N_P;
        float sp0 = softplus20(hp[0]);
        float sp1 = softplus20(hp[1]);
        float sp2 = softplus20(hp[2]);
        float denom = fmaxf(sp0 + sp1 + sp2, 1e-12f);
        float* o = HP + ((size_t)q * N_S + s) * 3;
        o[0] = sp0 / denom;
        o[1] = sp1 / denom;
        o[2] = sp2 / denom;
    }
}

// One q, 8 s-values (2 groups of 4), applied to TWO rows sharing the H reads.
// Hq is wave-uniform -> LDS broadcast reads (conflict-free). Math order is
// identical to the verified round-0 kernel.
__device__ __forceinline__ void computeQ2(const float4* __restrict__ Hq,
                                          float a0, float a1, float a2,
                                          float c0, float c1, float c2,
                                          float (&p)[SCHUNK], float (&p2)[SCHUNK]) {
    #pragma unroll
    for (int g = 0; g < SCHUNK / 4; ++g) {
        float4 b0 = Hq[3 * g], b1 = Hq[3 * g + 1], b2 = Hq[3 * g + 2];
        // layout per 4 s: [h00 h01 h02 h10][h11 h12 h20 h21][h22 h30 h31 h32]
        p [4*g+0] *= fmaf(b0.x, a0, fmaf(b0.y, a1, b0.z * a2));
        p2[4*g+0] *= fmaf(b0.x, c0, fmaf(b0.y, c1, b0.z * c2));
        p [4*g+1] *= fmaf(b0.w, a0, fmaf(b1.x, a1, b1.y * a2));
        p2[4*g+1] *= fmaf(b0.w, c0, fmaf(b1.x, c1, b1.y * c2));
        p [4*g+2] *= fmaf(b1.z, a0, fmaf(b1.w, a1, b2.x * a2));
        p2[4*g+2] *= fmaf(b1.z, c0, fmaf(b1.w, c1, b2.x * c2));
        p [4*g+3] *= fmaf(b2.y, a0, fmaf(b2.z, a1, b2.w * a2));
        p2[4*g+3] *= fmaf(b2.y, c0, fmaf(b2.z, c1, b2.w * c2));
    }
}

__global__ __launch_bounds__(THREADS) void main_kernel(
    const float* __restrict__ A, const float* __restrict__ coeff,
    const float* __restrict__ HP, const float* __restrict__ hrv,
    double* __restrict__ partials, int* __restrict__ cnt,
    float* __restrict__ out, int N) {
    __shared__ float hHs[N_Q * N_S * 3];     // 38400 B, q-major
    __shared__ float hrvl[N_S];
    __shared__ float covs[WAVES][BLK_ROWS];  // 4096 B
    __shared__ double redd[2];
    __shared__ double redf[WAVES];
    __shared__ int isLast;

    const int tid = threadIdx.x;
    const int lane = tid & 63;
    const int wave = tid >> 6;
    const int nbase = blockIdx.x * BLK_ROWS;

    // --- stage H (+hrv) into LDS once per block, coalesced float4 ---
    for (int i = tid; i < (N_Q * N_S * 3) / 4; i += THREADS)
        ((float4*)hHs)[i] = ((const float4*)HP)[i];
    if (tid < N_S) hrvl[tid] = hrv[tid];
    __syncthreads();

    // lane owns rows n0 = nbase+lane and n1 = nbase+64+lane (same for all waves)
    int n0 = nbase + lane;        if (n0 >= N) n0 = N - 1;
    int n1 = nbase + 64 + lane;   if (n1 >= N) n1 = N - 1;
    const float2* __restrict__ pA0 = (const float2*)A + (size_t)n0 * (ROW / 2);
    const float2* __restrict__ pA1 = (const float2*)A + (size_t)n1 * (ROW / 2);

    float prod0[SCHUNK], prod1[SCHUNK];
    #pragma unroll
    for (int i = 0; i < SCHUNK; ++i) { prod0[i] = 1.0f; prod1[i] = 1.0f; }

    // H base for this wave's s-chunk: q-row = 48 float4; wave offset 6*wave
    const float4* __restrict__ Hbase = (const float4*)hHs + 6 * wave;

    // window = 2 q = 6 floats/row; one-window A prefetch (12 floats live extra)
    float2 x0 = pA0[0], x1 = pA0[1], x2 = pA0[2];
    float2 y0 = pA1[0], y1 = pA1[1], y2 = pA1[2];

    #pragma unroll 5
    for (int w = 0; w < N_Q / 2; ++w) {
        const int nb = (w < N_Q / 2 - 1) ? 3 * w + 3 : 0;  // clamped, always valid
        float2 nx0 = pA0[nb], nx1 = pA0[nb + 1], nx2 = pA0[nb + 2];
        float2 ny0 = pA1[nb], ny1 = pA1[nb + 1], ny2 = pA1[nb + 2];
        const float4* Hq = Hbase + 96 * w;      // q = 2w -> row offset 2w*48
        computeQ2(Hq,      x0.x, x0.y, x1.x,  y0.x, y0.y, y1.x, prod0, prod1);
        computeQ2(Hq + 48, x1.y, x2.x, x2.y,  y1.y, y2.x, y2.y, prod0, prod1);
        x0 = nx0; x1 = nx1; x2 = nx2; y0 = ny0; y1 = ny1; y2 = ny2;
    }

    // ratio-weighted partials for both rows
    float acc0 = 0.0f, acc1 = 0.0f;
    const int s0 = wave * SCHUNK;
    #pragma unroll
    for (int i = 0; i < SCHUNK; ++i) {
        float wgt = hrvl[s0 + i];
        acc0 = fmaf(wgt, prod0[i], acc0);
        acc1 = fmaf(wgt, prod1[i], acc1);
    }
    covs[wave][lane] = acc0;
    covs[wave][64 + lane] = acc1;
    __syncthreads();

    // waves 0,1 finalize rows 0..63 / 64..127 (sequential 8-wave cov sum,
    // same association as the verified round-1 finalize: absmax stayed 0)
    if (wave < 2) {
        const int row = wave * 64 + lane;
        const int n = nbase + row;
        float cov = 0.0f;
        #pragma unroll
        for (int wv = 0; wv < WAVES; ++wv) cov += covs[wv][row];
        float term = 0.0f;
        if (n < N) { float c = coeff[n]; term = (c * c) / cov; }
        double td = (double)term;
        #pragma unroll
        for (int off = 32; off; off >>= 1) td += __shfl_down(td, off);
        if (lane == 0) redd[wave] = td;
    }
    __syncthreads();

    if (tid == 0) {
        partials[blockIdx.x] = redd[0] + redd[1];
        __threadfence();                 // release partial
        int v = atomicAdd(cnt, 1);
        isLast = (v == (int)gridDim.x - 1);
    }
    __syncthreads();

    if (isLast) {                        // last-finishing block reduces all
        __threadfence();                 // acquire
        double s = 0.0;
        for (int i = tid; i < (int)gridDim.x; i += THREADS) s += partials[i];
        #pragma unroll
        for (int off = 32; off; off >>= 1) s += __shfl_down(s, off);
        if (lane == 0) redf[wave] = s;
        __syncthreads();
        if (tid == 0) {
            double t = 0.0;
            #pragma unroll
            for (int wv = 0; wv < WAVES; ++wv) t += redf[wv];
            out[0] = (float)t;
        }
    }
}

extern "C" void kernel_launch(void* const* d_in, const int* in_sizes, int n_in,
                              void* d_out, int out_size, void* d_ws, size_t ws_size,
                              hipStream_t stream) {
    const float* A           = (const float*)d_in[0];  // [N, Q, P]
    const float* coeff       = (const float*)d_in[1];  // [N]
    const float* heads_param = (const float*)d_in[2];  // [S, Q, P]
    const float* hr_param    = (const float*)d_in[3];  // [S]
    const int N = in_sizes[1];
    const int nblocks = (N + BLK_ROWS - 1) / BLK_ROWS;  // 782

    char* ws = (char*)d_ws;
    double* partials = (double*)ws;
    int*   cnt = (int*)(ws + WS_CNT_OFF);
    float* HP  = (float*)(ws + WS_HP_OFF);
    float* hrv = (float*)(ws + WS_HRV_OFF);
    float* out = (float*)d_out;

    const int pre_blocks = (N_S * N_Q + THREADS - 1) / THREADS;  // 7
    precompute_kernel<<<pre_blocks, THREADS, 0, stream>>>(heads_param, hr_param,
                                                          HP, hrv, cnt);
    main_kernel<<<nblocks, THREADS, 0, stream>>>(A, coeff, HP, hrv, partials,
                                                 cnt, out, N);
}